// Round 9
// baseline (683.660 us; speedup 1.0000x reference)
//
#include <hip/hip_runtime.h>
#include <math.h>

#define BATCH 32
#define NN 1024
#define MM 1024
#define LPATH (NN + MM - 1)     // 2047

// ---------------- R9: fused band-sweep, register-resident streams ----------
// Geometry/handshake identical to R8 (verified absmax=0): band = 128 rows,
// 1 wave, lane owns rows 2l/2l+1, one 1088-step skewed sweep over all 1024
// cols; 32-col chunk handshake via monotone counter. R9 rebuilds the inner
// loop: 32-step superblock = 2x16-step halves with NAMED scalar register
// double-buffering (no indexed arrays, no copies) so tx/ty/Tv LDS reads are
// issued >=16 steps before use -- nothing waits on LDS on the DP chain.
#define PB 128
#define GB 8
#define SB 34                   // superblocks of 32 steps (1088 steps)
#define BAND_WORDS (136 * 64)   // 8704 decision words per band
#define BAT_WORDS3 (GB * BAND_WORDS)                  // 69632 words / batch
#define DEC3_WORDS ((size_t)BATCH * BAT_WORDS3)       // 2,228,224 words
#define BR3_OFFW DEC3_WORDS                           // bottom-row planes
#define BR3_SZ ((size_t)BATCH * GB * 1024)
#define CNT_OFFW (BR3_OFFW + BR3_SZ)                  // counters (b,r)
#define WS3_WORDS (CNT_OFFW + BATCH * GB)
#define REQ_WS3 (WS3_WORDS * 4)                       // ~9.96 MB

// Legacy (proven 557us) path requirement
#define DEC_WORDS_PER_BATCH ((NN / 4) * (MM / 4))     // 65536
#define REQ_WS ((size_t)BATCH * DEC_WORDS_PER_BATCH * 4)   // 8 MB

__global__ void init_kernel(float* out) { out[0] = 0.0f; }

__global__ void init4(unsigned* __restrict__ wsu, float* __restrict__ out)
{
    const int t = threadIdx.x;
    if (t == 0) out[0] = 0.0f;
    if (t < BATCH * GB) wsu[CNT_OFFW + t] = 0u;
}

__device__ __forceinline__ float wave_shr1(float v)
{
    return __int_as_float(__builtin_amdgcn_update_dpp(
        __float_as_int(v), __float_as_int(v), 0x138, 0xF, 0xF, false));
}

// One DP step (2 cells), math VERBATIM from the R5/R6/R8-verified body.
// Captures: u0, l, D0, D1, up0prev, dg0init, word, botL from scope.
#define STEP(K, TX, TY, TV) do {                                             \
    const int u_ = u0 + (K);                                                 \
    const int jq_ = u_ - l;                                                  \
    const bool act_ = (jq_ >= 0) && (jq_ < MM);                              \
    const float sh_ = wave_shr1(D1);                                         \
    const float up0_ = (l == 0) ? (TV) : sh_;                                \
    const float dg0_ = (jq_ == 0) ? dg0init : up0prev;                       \
    const float dx0_ = px0 - (TX), dy0_ = py0 - (TY);                        \
    const float c0_ = __builtin_amdgcn_sqrtf(dx0_ * dx0_ + dy0_ * dy0_);     \
    const float mn0_ = fminf(dg0_, fminf(up0_, D0));                         \
    const float D0n_ = c0_ + mn0_;                                           \
    const unsigned m0_ = (mn0_ == dg0_) ? 0u : ((mn0_ == up0_) ? 1u : 2u);   \
    const float dg1_ = D0;                                                   \
    const float dx1_ = px1 - (TX), dy1_ = py1 - (TY);                        \
    const float c1_ = __builtin_amdgcn_sqrtf(dx1_ * dx1_ + dy1_ * dy1_);     \
    const float mn1_ = fminf(dg1_, fminf(D0n_, D1));                         \
    const float D1n_ = c1_ + mn1_;                                           \
    const unsigned m1_ = (mn1_ == dg1_) ? 0u : ((mn1_ == D0n_) ? 1u : 2u);   \
    word |= (m0_ | (m1_ << 2)) << (4 * ((K) & 7));                           \
    if (act_) { D0 = D0n_; D1 = D1n_; }                                      \
    up0prev = up0_;                                                          \
    if (l == 63 && act_) botL[jq_ & 63] = D1n_;                              \
} while (0)

// Load one 16-col register set (named scalars -> stays in VGPRs).
#define LOADSET(X, Y, UB) do {                                               \
    const int b_ = 63 + (UB) - l;                                            \
    X##0 = txA[b_ + 0];  X##1 = txA[b_ + 1];  X##2 = txA[b_ + 2];            \
    X##3 = txA[b_ + 3];  X##4 = txA[b_ + 4];  X##5 = txA[b_ + 5];            \
    X##6 = txA[b_ + 6];  X##7 = txA[b_ + 7];  X##8 = txA[b_ + 8];            \
    X##9 = txA[b_ + 9];  X##10 = txA[b_ + 10]; X##11 = txA[b_ + 11];         \
    X##12 = txA[b_ + 12]; X##13 = txA[b_ + 13]; X##14 = txA[b_ + 14];        \
    X##15 = txA[b_ + 15];                                                    \
    Y##0 = tyA[b_ + 0];  Y##1 = tyA[b_ + 1];  Y##2 = tyA[b_ + 2];            \
    Y##3 = tyA[b_ + 3];  Y##4 = tyA[b_ + 4];  Y##5 = tyA[b_ + 5];            \
    Y##6 = tyA[b_ + 6];  Y##7 = tyA[b_ + 7];  Y##8 = tyA[b_ + 8];            \
    Y##9 = tyA[b_ + 9];  Y##10 = tyA[b_ + 10]; Y##11 = tyA[b_ + 11];         \
    Y##12 = tyA[b_ + 12]; Y##13 = tyA[b_ + 13]; Y##14 = tyA[b_ + 14];        \
    Y##15 = tyA[b_ + 15];                                                    \
} while (0)

// 16 steps consuming set X/Y with Tv quads T0..T3; writes 2 decision words.
#define HALF(U0, X, Y, T0, T1, T2, T3) do {                                  \
    const int u0 = (U0);                                                     \
    unsigned word = 0u;                                                      \
    STEP(0,  X##0,  Y##0,  T0.x);  STEP(1,  X##1,  Y##1,  T0.y);             \
    STEP(2,  X##2,  Y##2,  T0.z);  STEP(3,  X##3,  Y##3,  T0.w);             \
    STEP(4,  X##4,  Y##4,  T1.x);  STEP(5,  X##5,  Y##5,  T1.y);             \
    STEP(6,  X##6,  Y##6,  T1.z);  STEP(7,  X##7,  Y##7,  T1.w);             \
    decBand[(u0 >> 3) * 64 + l] = word;                                      \
    word = 0u;                                                               \
    STEP(8,  X##8,  Y##8,  T2.x);  STEP(9,  X##9,  Y##9,  T2.y);             \
    STEP(10, X##10, Y##10, T2.z);  STEP(11, X##11, Y##11, T2.w);             \
    STEP(12, X##12, Y##12, T3.x);  STEP(13, X##13, Y##13, T3.y);             \
    STEP(14, X##14, Y##14, T3.z);  STEP(15, X##15, Y##15, T3.w);             \
    decBand[((u0 >> 3) + 1) * 64 + l] = word;                                \
} while (0)

__global__ __launch_bounds__(64, 1) void dtw_dp4(
    const float* __restrict__ preds, const float* __restrict__ targs,
    unsigned* __restrict__ wsu)
{
    const int blk = blockIdx.x;
    const int b = blk >> 3, r = blk & 7;
    const int l = threadIdx.x;
    const float INF = __builtin_inff();

    __shared__ __align__(16) float txA[1184], tyA[1184];  // skew-padded stream
    __shared__ __align__(16) float TLb[2][32];            // top-row chunk dbuf
    __shared__ float botL[64];                            // bottom-row ring

    for (int i = l; i < 1184; i += 64) { txA[i] = 0.f; tyA[i] = 0.f; }
    if (l < 32) { TLb[0][l] = INF; TLb[1][l] = INF; }

    {   // stage targ cols (col j basis x,y at [63+j])
        const float4* tg4 = (const float4*)targs + (size_t)b * MM;
        for (int j = l; j < MM; j += 64) {
            const float4 v = tg4[j];
            txA[63 + j] = v.x; tyA[63 + j] = v.y;
        }
    }
    const float4* pp4 = (const float4*)preds + (size_t)b * NN + r * PB;
    const float4 p0 = pp4[2 * l], p1 = pp4[2 * l + 1];
    const float px0 = p0.x, py0 = p0.y, px1 = p1.x, py1 = p1.y;

    unsigned* __restrict__ decBand =
        wsu + (size_t)b * BAT_WORDS3 + (size_t)r * BAND_WORDS;
    float* browAll = (float*)(wsu + BR3_OFFW);
    const float* browPrev = browAll + ((size_t)b * GB + ((r > 0) ? r - 1 : 0)) * 1024;
    float* browMine = browAll + ((size_t)b * GB + r) * 1024;
    unsigned* cntPrev = wsu + CNT_OFFW + b * GB + ((r > 0) ? r - 1 : 0);
    unsigned* cntMine = wsu + CNT_OFFW + b * GB + r;

    float D0 = INF, D1 = INF, up0prev = INF;
    const float dg0init = (l == 0) ? ((r == 0) ? 0.0f : INF) : INF;
    __syncthreads();

    // prologue: acquire + stage chunk 0
    if (r > 0) {
        while (__hip_atomic_load(cntPrev, __ATOMIC_ACQUIRE,
                                 __HIP_MEMORY_SCOPE_AGENT) < 1u)
            __builtin_amdgcn_s_sleep(1);
        if (l < 32)
            TLb[0][l] = __int_as_float(__hip_atomic_load(
                (const unsigned*)&browPrev[l],
                __ATOMIC_RELAXED, __HIP_MEMORY_SCOPE_AGENT));
        __syncthreads();
    }

    float ax0, ax1, ax2, ax3, ax4, ax5, ax6, ax7,
          ax8, ax9, ax10, ax11, ax12, ax13, ax14, ax15;
    float ay0, ay1, ay2, ay3, ay4, ay5, ay6, ay7,
          ay8, ay9, ay10, ay11, ay12, ay13, ay14, ay15;
    float bx0, bx1, bx2, bx3, bx4, bx5, bx6, bx7,
          bx8, bx9, bx10, bx11, bx12, bx13, bx14, bx15;
    float by0, by1, by2, by3, by4, by5, by6, by7,
          by8, by9, by10, by11, by12, by13, by14, by15;
    float4 tva0, tva1, tva2, tva3, tvb0, tvb1, tvb2, tvb3;

    LOADSET(ax, ay, 0);
    tva0 = *(const float4*)&TLb[0][0];  tva1 = *(const float4*)&TLb[0][4];
    tva2 = *(const float4*)&TLb[0][8];  tva3 = *(const float4*)&TLb[0][12];

    #pragma unroll 1
    for (int c = 0; c < SB; ++c) {
        // ---- half 1: consume A, issue B (+TvB) for steps 32c+16..+31 ----
        LOADSET(bx, by, 32 * c + 16);
        tvb0 = *(const float4*)&TLb[c & 1][16];
        tvb1 = *(const float4*)&TLb[c & 1][20];
        tvb2 = *(const float4*)&TLb[c & 1][24];
        tvb3 = *(const float4*)&TLb[c & 1][28];
        __builtin_amdgcn_sched_barrier(0);     // keep loads issued early
        HALF(32 * c, ax, ay, tva0, tva1, tva2, tva3);
        // ---- half 2: consume B, issue A for steps 32(c+1)..+15 ----
        LOADSET(ax, ay, 32 * (c + 1));
        __builtin_amdgcn_sched_barrier(0);
        HALF(32 * c + 16, bx, by, tvb0, tvb1, tvb2, tvb3);
        // ---- handshake (verbatim R8, verified) ----
        if (r < GB - 1 && c >= 2) {
            const int ch = c - 2;
            if (l < 32)
                __hip_atomic_store((unsigned*)&browMine[32 * ch + l],
                    __float_as_uint(botL[(32 * ch + l) & 63]),
                    __ATOMIC_RELAXED, __HIP_MEMORY_SCOPE_AGENT);
            __threadfence();
            if (l == 0)
                __hip_atomic_store(cntMine, (unsigned)(ch + 1),
                                   __ATOMIC_RELEASE, __HIP_MEMORY_SCOPE_AGENT);
        }
        const int k1 = c + 1;
        if (r > 0 && k1 <= 31) {
            while (__hip_atomic_load(cntPrev, __ATOMIC_ACQUIRE,
                                     __HIP_MEMORY_SCOPE_AGENT) < (unsigned)(k1 + 1))
                __builtin_amdgcn_s_sleep(1);
            if (l < 32)
                TLb[k1 & 1][l] = __int_as_float(__hip_atomic_load(
                    (const unsigned*)&browPrev[32 * k1 + l],
                    __ATOMIC_RELAXED, __HIP_MEMORY_SCOPE_AGENT));
        }
        if (c < SB - 1) {        // TvA for first half of next superblock
            tva0 = *(const float4*)&TLb[(c + 1) & 1][0];
            tva1 = *(const float4*)&TLb[(c + 1) & 1][4];
            tva2 = *(const float4*)&TLb[(c + 1) & 1][8];
            tva3 = *(const float4*)&TLb[(c + 1) & 1][12];
        }
    }
}

// ---- Backtrack + loss: 32 blocks x 256 threads (R5-proven walk, R8 layout) --
__global__ __launch_bounds__(256, 1) void dtw_bt(
    const float* __restrict__ preds, const float* __restrict__ targs,
    const float* __restrict__ subcoef, const unsigned* __restrict__ wsu,
    float* __restrict__ out)
{
    const int b = blockIdx.x, t = threadIdx.x;
    __shared__ float pxA[NN], pyA[NN], txA[MM], tyA[MM];   // 16 KB
    __shared__ unsigned path[2048];                        // 8 KB
    __shared__ int sN;
    __shared__ float wsum[4];

    for (int it = 0; it < 4; ++it) {
        const int idx = it * 256 + t;
        const float4 p4 = ((const float4*)preds)[(size_t)b * NN + idx];
        pxA[idx] = p4.x; pyA[idx] = p4.y;
        const float4 t4 = ((const float4*)targs)[(size_t)b * MM + idx];
        txA[idx] = t4.x; tyA[idx] = t4.y;
    }
    __syncthreads();

    if (t == 0) {
        const unsigned* __restrict__ decB = wsu + (size_t)b * BAT_WORDS3;
        int i = NN - 1, j = MM - 1, n = 0;
        int cwidx = -1; unsigned cw = 0;
        while (true) {
            path[n++] = ((unsigned)i << 16) | (unsigned)j;
            if ((i | j) == 0) break;
            const int ll = (i & 127) >> 1;
            const int ss = ll + j;
            const int widx = (i >> 7) * BAND_WORDS + (ss >> 3) * 64 + ll;
            if (widx != cwidx) { cw = decB[widx]; cwidx = widx; }
            const unsigned m = (cw >> ((ss & 7) * 4 + (i & 1) * 2)) & 3u;
            i -= (m != 2u); j -= (m != 1u);
        }
        sN = n;
    }
    __syncthreads();

    const float sc0 = subcoef[0], sc1 = subcoef[1];
    const int n = sN;
    float acc = 0.0f;
    for (int p = t; p < n; p += 256) {
        const unsigned e = path[p];
        const int i = (int)(e >> 16), j = (int)(e & 0xffffu);
        acc += fabsf(pxA[i] - txA[j]) * sc0 + fabsf(pyA[i] - tyA[j]) * sc1;
    }
    #pragma unroll
    for (int o = 32; o > 0; o >>= 1) acc += __shfl_down(acc, o);
    if ((t & 63) == 0) wsum[t >> 6] = acc;
    __syncthreads();
    if (t == 0) atomicAdd(out, (wsum[0] + wsum[1]) + (wsum[2] + wsum[3]));
}

// =================== Legacy proven path (557us, needs 8MB) ===================
__device__ inline void bt_walk4(const unsigned* __restrict__ sdec, int roff,
                                int iLow, int& i, int& j, int& n,
                                unsigned* __restrict__ path)
{
    int ri = i >> 2, jc = j >> 2;
    unsigned w = sdec[(ri - roff) * 256 + jc];
    while (true) {
        const int base = (ri - roff) * 256 + jc;
        const unsigned wl = sdec[(jc > 0)    ? base - 1   : base];
        const unsigned wu = sdec[(ri > roff) ? base - 256 : base];
        const unsigned wd = sdec[(ri > roff && jc > 0) ? base - 257 : base];
        bool done = false, susp = false;
        while (true) {
            path[n++] = ((unsigned)i << 16) | (unsigned)j;
            if ((i | j) == 0) { done = true; break; }
            const unsigned m = (w >> (((i & 3) * 4 + (j & 3)) * 2)) & 3u;
            i -= (m != 2u); j -= (m != 1u);
            if (i < iLow) { susp = true; break; }
            if ((i >> 2) != ri || (j >> 2) != jc) break;
        }
        if (done || susp) break;
        const int nri = i >> 2, njc = j >> 2;
        w = (nri == ri) ? wl : ((njc == jc) ? wu : wd);
        ri = nri; jc = njc;
    }
}

#define RRL 4
#define CCL 4
#define LANES 64
#define NWAVE 4
#define TPBL (MM / 4)
#define NSUP (TPBL + LANES - 1)
#define LAG 72
#define TOTL (NSUP + (NWAVE - 1) * LAG)
#define DEPTH 32

__global__ __launch_bounds__(256, 1) void dtw_fused_legacy(
    const float* __restrict__ preds, const float* __restrict__ targs,
    const float* __restrict__ subcoef, unsigned* __restrict__ dec,
    float* __restrict__ out)
{
    const int b = blockIdx.x, t = threadIdx.x;
    const int l = t & 63, w = t >> 6;
    const float INF = __builtin_inff();

    __shared__ float pxA[NN], pyA[NN], txA[MM], tyA[MM];
    __shared__ float4 ring[NWAVE - 1][DEPTH];
    __shared__ unsigned sdec[128 * 256];
    __shared__ unsigned path[LPATH + 1];
    __shared__ int sI, sJ, sN;
    __shared__ float wsum[NWAVE];

    for (int it = 0; it < NN / 256; ++it) {
        const int idx = it * 256 + t;
        const float4 p4 = ((const float4*)preds)[(size_t)b * NN + idx];
        pxA[idx] = p4.x; pyA[idx] = p4.y;
        const float4 t4 = ((const float4*)targs)[(size_t)b * MM + idx];
        txA[idx] = t4.x; tyA[idx] = t4.y;
    }
    __syncthreads();

    const int i0 = (w << 8) + (l << 2);
    const float4 px4 = ((const float4*)pxA)[i0 >> 2];
    const float4 py4 = ((const float4*)pyA)[i0 >> 2];
    const float px[RRL] = {px4.x, px4.y, px4.z, px4.w};
    const float py[RRL] = {py4.x, py4.y, py4.z, py4.w};
    unsigned* __restrict__ decW =
        dec + (size_t)b * DEC_WORDS_PER_BATCH + ((size_t)w << 14) + (size_t)l;

    float Dp[RRL], Dbot[CCL], bv[CCL];
    #pragma unroll
    for (int r = 0; r < RRL; ++r) Dp[r] = INF;
    #pragma unroll
    for (int c = 0; c < CCL; ++c) { Dbot[c] = INF; bv[c] = INF; }
    float bndRet = (w == 0 && l == 0) ? 0.0f : INF;
    float4 gcur = make_float4(INF, INF, INF, INF);
    float4 tx4 = ((const float4*)txA)[0], ty4 = ((const float4*)tyA)[0];
    const float4* __restrict__ ringR = ring[(w > 0) ? (w - 1) : 0];

    for (int u = 0; u < TOTL; ++u) {
        const int ul = u - LAG * w;
        if (l == 0) {
            const bool gb = (w > 0) && (ul >= 0) && (ul < TPBL);
            bv[0] = gb ? gcur.x : INF; bv[1] = gb ? gcur.y : INF;
            bv[2] = gb ? gcur.z : INF; bv[3] = gb ? gcur.w : INF;
        }
        const bool act = (ul >= l) && (ul < l + TPBL);
        if (act) {
            const float cx[CCL] = {tx4.x, tx4.y, tx4.z, tx4.w};
            const float cy[CCL] = {ty4.x, ty4.y, ty4.z, ty4.w};
            float cost[RRL][CCL];
            #pragma unroll
            for (int c = 0; c < CCL; ++c)
                #pragma unroll
                for (int r = 0; r < RRL; ++r) {
                    const float dx = px[r] - cx[c], dy = py[r] - cy[c];
                    cost[r][c] = __builtin_amdgcn_sqrtf(dx * dx + dy * dy);
                }
            unsigned word = 0;
            #pragma unroll
            for (int c = 0; c < CCL; ++c) {
                float up = bv[c];
                float dg = (c == 0) ? bndRet : bv[c - 1];
                #pragma unroll
                for (int r = 0; r < RRL; ++r) {
                    const float lf = Dp[r];
                    const unsigned m = (dg <= up && dg <= lf) ? 0u
                                     : ((up <= lf) ? 1u : 2u);
                    const float D = cost[r][c] + fminf(dg, fminf(up, lf));
                    word |= m << ((r * 4 + c) * 2);
                    dg = lf; up = D; Dp[r] = D;
                }
                Dbot[c] = up;
            }
            decW[(ul & 255) << 6] = word;
            if (l == LANES - 1 && w < NWAVE - 1)
                ring[w][ul & (DEPTH - 1)] =
                    make_float4(Dbot[0], Dbot[1], Dbot[2], Dbot[3]);
        }
        bndRet = bv[CCL - 1];
        #pragma unroll
        for (int c = 0; c < CCL; ++c) bv[c] = __shfl_up(Dbot[c], 1);
        const int un = ul + 1;
        if (un >= l && un < l + TPBL) {
            const int jn = CCL * (un - l);
            tx4 = ((const float4*)txA)[jn >> 2];
            ty4 = ((const float4*)tyA)[jn >> 2];
        }
        if (w > 0 && un >= 0 && un < TPBL)
            gcur = ringR[(un + 63) & (DEPTH - 1)];
        if ((u & 7) == 7) __syncthreads();
    }

    __threadfence_block();
    __syncthreads();

    const unsigned* __restrict__ decB = dec + (size_t)b * DEC_WORDS_PER_BATCH;
    {
        const uint4* g4 = (const uint4*)(decB + 32768);
        for (int k = t; k < 8192; k += 256) {
            const uint4 v = g4[k];
            const int kb = k << 2;
            const int wv = kb >> 14;
            const int rem = kb & 16383;
            const int q = rem >> 6;
            const int lb = rem & 63;
            const unsigned wd[4] = {v.x, v.y, v.z, v.w};
            #pragma unroll
            for (int e = 0; e < 4; ++e) {
                const int ll = lb + e;
                const int row = (wv << 6) + ll;
                const int jc = (q - ll) & 255;
                sdec[(row << 8) + jc] = wd[e];
            }
        }
    }
    __syncthreads();
    if (t == 0) {
        int i = NN - 1, j = MM - 1, n = 0;
        bt_walk4(sdec, 128, 512, i, j, n, path);
        sI = i; sJ = j; sN = n;
    }
    __syncthreads();
    {
        const uint4* g4 = (const uint4*)decB;
        for (int k = t; k < 8192; k += 256) {
            const uint4 v = g4[k];
            const int kb = k << 2;
            const int wv = kb >> 14;
            const int rem = kb & 16383;
            const int q = rem >> 6;
            const int lb = rem & 63;
            const unsigned wd[4] = {v.x, v.y, v.z, v.w};
            #pragma unroll
            for (int e = 0; e < 4; ++e) {
                const int ll = lb + e;
                const int row = (wv << 6) + ll;
                const int jc = (q - ll) & 255;
                sdec[(row << 8) + jc] = wd[e];
            }
        }
    }
    __syncthreads();
    if (t == 0) {
        int i = sI, j = sJ, n = sN;
        bt_walk4(sdec, 0, 0, i, j, n, path);
        sN = n;
    }
    __syncthreads();

    const float sc0 = subcoef[0], sc1 = subcoef[1];
    const int n = sN;
    float acc = 0.0f;
    for (int p = t; p < n; p += 256) {
        const unsigned e = path[p];
        const int i = (int)(e >> 16), j = (int)(e & 0xffffu);
        acc += fabsf(pxA[i] - txA[j]) * sc0 + fabsf(pyA[i] - tyA[j]) * sc1;
    }
    #pragma unroll
    for (int o = 32; o > 0; o >>= 1) acc += __shfl_down(acc, o);
    if ((t & 63) == 0) wsum[t >> 6] = acc;
    __syncthreads();
    if (t == 0) atomicAdd(out, (wsum[0] + wsum[1]) + (wsum[2] + wsum[3]));
}

// ------------- Fallback (only if ws too small for everything) ----------------
__global__ __launch_bounds__(256) void dtw_fallback(
    const float* __restrict__ preds, const float* __restrict__ targs,
    const float* __restrict__ subcoef, unsigned* __restrict__ dec,
    float* __restrict__ out)
{
    const int b = blockIdx.x;
    const int t = threadIdx.x;
    const float INF = __builtin_inff();
    __shared__ float px[NN], py[NN];
    __shared__ float txy[2 * MM];
    __shared__ float bbuf[2][256];

    for (int it = 0; it < NN / 256; ++it) {
        const int idx = it * 256 + t;
        const float4 p4 = ((const float4*)preds)[(size_t)b * NN + idx];
        px[idx] = p4.x; py[idx] = p4.y;
        const float4 t4 = ((const float4*)targs)[(size_t)b * MM + idx];
        txy[2 * idx] = t4.x; txy[2 * idx + 1] = t4.y;
    }
    bbuf[0][t] = INF; bbuf[1][t] = INF;
    __syncthreads();

    float pxr[4], pyr[4], Dp[4];
    #pragma unroll
    for (int r = 0; r < 4; ++r) {
        pxr[r] = px[4 * t + r]; pyr[r] = py[4 * t + r]; Dp[r] = INF;
    }
    float dgB = (t == 0) ? 0.0f : INF;
    unsigned packed = 0;
    unsigned* decB = dec + (size_t)b * 65536;
    for (int s = 0; s < MM + 255; ++s) {
        const int j = s - t;
        const float upB = (t == 0) ? INF : bbuf[(s + 1) & 1][t - 1];
        if (j >= 0 && j < MM) {
            const float txj = txy[2 * j], tyj = txy[2 * j + 1];
            float up = upB, dg = dgB;
            unsigned mbits = 0;
            #pragma unroll
            for (int r = 0; r < 4; ++r) {
                const float dx = pxr[r] - txj, dy = pyr[r] - tyj;
                const float c = sqrtf(dx * dx + dy * dy);
                const float lf = Dp[r];
                const unsigned m = (dg <= up && dg <= lf) ? 0u
                                 : ((up <= lf) ? 1u : 2u);
                mbits |= m << (r * 8 + (j & 3) * 2);
                const float Dc = c + fminf(up, fminf(dg, lf));
                dg = lf; up = Dc; Dp[r] = Dc;
            }
            packed |= mbits;
            if ((j & 3) == 3) { decB[(unsigned)t * 256 + (j >> 2)] = packed; packed = 0; }
            bbuf[s & 1][t] = Dp[3];
        }
        dgB = upB;
        __syncthreads();
    }
    __threadfence_block();
    __syncthreads();
    if (t == 0) {
        const float sc0 = subcoef[0], sc1 = subcoef[1];
        int i = NN - 1, jj = MM - 1;
        float loss = 0.0f;
        int ti = i >> 2, tj = jj >> 2;
        unsigned wv = decB[ti * 256 + tj];
        while (true) {
            const int tjl = (tj > 0) ? tj - 1 : 0;
            const int til = (ti > 0) ? ti - 1 : 0;
            const unsigned wl = decB[ti * 256 + tjl];
            const unsigned wu = decB[til * 256 + tj];
            const unsigned wd = decB[til * 256 + tjl];
            bool done = false;
            while (true) {
                loss += fabsf(px[i] - txy[2 * jj]) * sc0
                      + fabsf(py[i] - txy[2 * jj + 1]) * sc1;
                if ((i | jj) == 0) { done = true; break; }
                const unsigned m = (wv >> (((i & 3) * 4 + (jj & 3)) * 2)) & 3u;
                i -= (m != 2u); jj -= (m != 1u);
                if ((i >> 2) != ti || (jj >> 2) != tj) break;
            }
            if (done) break;
            const int nti = i >> 2, ntj = jj >> 2;
            wv = (nti == ti) ? wl : ((ntj == tj) ? wu : wd);
            ti = nti; tj = ntj;
        }
        atomicAdd(out, loss);
    }
}

extern "C" void kernel_launch(void* const* d_in, const int* in_sizes, int n_in,
                              void* d_out, int out_size, void* d_ws, size_t ws_size,
                              hipStream_t stream) {
    const float* preds   = (const float*)d_in[0];
    const float* targs   = (const float*)d_in[1];
    const float* subcoef = (const float*)d_in[2];
    float* out = (float*)d_out;

    if (ws_size >= REQ_WS3) {
        unsigned* wsu = (unsigned*)d_ws;
        init4<<<1, 256, 0, stream>>>(wsu, out);
        dtw_dp4<<<BATCH * GB, 64, 0, stream>>>(preds, targs, wsu);
        dtw_bt<<<BATCH, 256, 0, stream>>>(preds, targs, subcoef, wsu, out);
    } else if (ws_size >= REQ_WS) {
        unsigned* dec = (unsigned*)d_ws;
        init_kernel<<<1, 1, 0, stream>>>(out);
        dtw_fused_legacy<<<BATCH, 256, 0, stream>>>(preds, targs, subcoef, dec, out);
    } else {
        unsigned* dec = (unsigned*)d_ws;
        init_kernel<<<1, 1, 0, stream>>>(out);
        dtw_fallback<<<BATCH, 256, 0, stream>>>(preds, targs, subcoef, dec, out);
    }
}

// Round 10
// 562.480 us; speedup vs baseline: 1.2154x; 1.2154x over previous
//
#include <hip/hip_runtime.h>
#include <math.h>

#define BATCH 32
#define NN 1024
#define MM 1024
#define LPATH (NN + MM - 1)     // 2047

// ---------------- Wavefront-panel geometry (R5, proven 540us total) ---------
#define PB 128                  // panel rows
#define PQ 128                  // panel cols
#define GB 8                    // bands (rows of panels)
#define GH 8                    // panel columns
#define PAN_WORDS 1536          // 24 sblk x 64 lanes (4 bits/step/lane)
#define BAT_WORDS (GB * GH * PAN_WORDS)               // 98304 words / batch
#define BAND_W (GH * PAN_WORDS)                       // 12288 words / band
#define RCPL (9 * 1024)                               // rcol/brow plane floats
#define RC_OFFW ((size_t)BATCH * BAT_WORDS)
#define BR_OFFW (RC_OFFW + (size_t)BATCH * RCPL)
#define WS_WORDS (BR_OFFW + (size_t)BATCH * RCPL)
#define REQ_WS_NEW (WS_WORDS * 4)                     // ~14.3 MB

// Legacy (proven 557us) path requirement
#define DEC_WORDS_PER_BATCH ((NN / 4) * (MM / 4))     // 65536
#define REQ_WS ((size_t)BATCH * DEC_WORDS_PER_BATCH * 4)   // 8 MB

__global__ void init_kernel(float* out) { out[0] = 0.0f; }

// ---- init (R5 verbatim): INF boundary planes (c=0 / r=0) + out=0 -----------
__global__ void init2(float* __restrict__ ws, float* __restrict__ out)
{
    const int b = blockIdx.x, t = threadIdx.x;
    const float INF = __builtin_inff();
    if (b == 0 && t == 0) out[0] = 0.0f;
    float* rc0 = ws + RC_OFFW + (size_t)b * RCPL;     // rcol[b][0][*]
    float* br0 = ws + BR_OFFW + (size_t)b * RCPL;     // brow[b][0][*]
    for (int i = t; i < 1024; i += 256) { rc0[i] = INF; br0[i] = INF; }
}

__device__ __forceinline__ float wave_shr1(float v)
{
    return __int_as_float(__builtin_amdgcn_update_dpp(
        __float_as_int(v), __float_as_int(v), 0x138, 0xF, 0xF, false));
}

// ---- Panel DP kernel (R5 VERBATIM, measured ~380us over 15 launches) --------
__global__ __launch_bounds__(64, 1) void dtw_panel(
    const float* __restrict__ preds, const float* __restrict__ targs,
    float* __restrict__ ws, const int diag)
{
    const int b = blockIdx.y;
    const int r0 = (diag > GH - 1) ? diag - (GH - 1) : 0;
    const int r = r0 + blockIdx.x;
    const int c = diag - r;
    const int l = threadIdx.x;
    const float INF = __builtin_inff();

    __shared__ __align__(16) float txP[260], tyP[260];   // padded col streams
    __shared__ __align__(16) float TL[200];              // top row stream
    __shared__ __align__(16) float botL[128];            // bottom row collect

    // pads (reads for inactive jq land here; values unused)
    if (l < 63) { txP[l] = 0.f; tyP[l] = 0.f; }
    txP[191 + l] = 0.f; tyP[191 + l] = 0.f;
    if (l < 6) { txP[255 + l] = 0.f; tyP[255 + l] = 0.f; }
    TL[128 + l] = INF; if (l < 8) TL[192 + l] = INF;

    // stage targ cols [128c .. 128c+127] (basis x,y = features 0,1)
    const float4* tg4 = (const float4*)targs + (size_t)b * MM + c * PQ;
    {
        const float4 a = tg4[l], e = tg4[64 + l];
        txP[63 + l] = a.x;      tyP[63 + l] = a.y;
        txP[63 + 64 + l] = e.x; tyP[63 + 64 + l] = e.y;
    }
    // top boundary row (brow[b][r] holds D of global row 128r-1; r=0 -> INF)
    const float* browR = ws + BR_OFFW + ((size_t)b * 9 + r) * 1024 + c * PQ;
    TL[l] = browR[l]; TL[64 + l] = browR[64 + l];

    // pred rows
    const float4* pp4 = (const float4*)preds + (size_t)b * NN + r * PB;
    const float4 p0 = pp4[2 * l], p1 = pp4[2 * l + 1];
    const float px0 = p0.x, py0 = p0.y, px1 = p1.x, py1 = p1.y;

    // left boundary (rcol[b][c] holds D of global col 128c-1; c=0 -> INF)
    const float* rc = ws + RC_OFFW + ((size_t)b * 9 + c) * 1024 + r * PB;
    float D0 = rc[2 * l], D1 = rc[2 * l + 1];
    const float corner = (c == 0) ? ((r == 0) ? 0.0f : INF) : browR[-1];
    const float dg0init = (l == 0) ? corner : rc[2 * l - 1];

    unsigned* __restrict__ decP = (unsigned*)ws + (size_t)b * BAT_WORDS
                                + (size_t)(r * GH + c) * PAN_WORDS + l;
    __syncthreads();

    // 8-slot register ring for tx/ty, prefetch distance 4 steps
    float txb[8], tyb[8];
    #pragma unroll
    for (int k = 0; k < 4; ++k) { txb[k] = txP[63 + k - l]; tyb[k] = tyP[63 + k - l]; }
    float up0prev = INF;

    for (int it = 0; it < 24; ++it) {
        const int s0 = it * 8;
        const float4 T4a = *(const float4*)&TL[s0];
        const float4 T4b = *(const float4*)&TL[s0 + 4];
        const float Tv[8] = {T4a.x, T4a.y, T4a.z, T4a.w,
                             T4b.x, T4b.y, T4b.z, T4b.w};
        unsigned word = 0;
        #pragma unroll
        for (int k = 0; k < 8; ++k) {
            const int s = s0 + k;
            const int jq = s - l;
            txb[(k + 4) & 7] = txP[63 + jq + 4];
            tyb[(k + 4) & 7] = tyP[63 + jq + 4];
            const float sh = wave_shr1(D1);           // lane l-1's D1, no DS
            const float up0 = (l == 0) ? Tv[k] : sh;
            const float dg0 = (jq == 0) ? dg0init : up0prev;
            const float tx = txb[k], ty = tyb[k];
            // cell (row 2l): math identical to proven kernel (absmax=0)
            const float dx0 = px0 - tx, dy0 = py0 - ty;
            const float c0 = __builtin_amdgcn_sqrtf(dx0 * dx0 + dy0 * dy0);
            const float mn0 = fminf(dg0, fminf(up0, D0));
            const float D0n = c0 + mn0;
            const unsigned m0 = (mn0 == dg0) ? 0u : ((mn0 == up0) ? 1u : 2u);
            // cell (row 2l+1)
            const float dg1 = D0;
            const float dx1 = px1 - tx, dy1 = py1 - ty;
            const float c1 = __builtin_amdgcn_sqrtf(dx1 * dx1 + dy1 * dy1);
            const float mn1 = fminf(dg1, fminf(D0n, D1));
            const float D1n = c1 + mn1;
            const unsigned m1 = (mn1 == dg1) ? 0u : ((mn1 == D0n) ? 1u : 2u);
            word |= (m0 | (m1 << 2)) << (4 * k);
            const bool act = (jq >= 0) && (jq < PQ);
            if (act) { D0 = D0n; D1 = D1n; }
            up0prev = up0;
            if (l == 63 && act) botL[jq] = D1n;   // band bottom row
        }
        decP[it * 64] = word;                     // coalesced 256B store
    }

    // publish right column (D regs frozen at jq=127 by predication)
    float* rcw = ws + RC_OFFW + ((size_t)b * 9 + (c + 1)) * 1024 + r * PB;
    rcw[2 * l] = D0; rcw[2 * l + 1] = D1;
    __syncthreads();
    float* brw = ws + BR_OFFW + ((size_t)b * 9 + (r + 1)) * 1024 + c * PQ;
    brw[l] = botL[l]; brw[64 + l] = botL[64 + l];
}

// ---- Backtrack + loss: 32 blocks x 256 threads ------------------------------
// R10 change: per-band LDS double-buffer with copy/walk OVERLAP. Thread 0
// walks band r out of sbuf[r&1] (LDS ~2x faster per move than L2) while
// threads 1..255 copy band r-1 into sbuf[(r-1)&1]; barrier-separated, no
// flags. Walk logic/word layout verbatim from the R5-proven walk, with
// band-relative addressing (i>>7 == r inside the round).
__global__ __launch_bounds__(256, 1) void dtw_bt(
    const float* __restrict__ preds, const float* __restrict__ targs,
    const float* __restrict__ subcoef, const unsigned* __restrict__ wsu,
    float* __restrict__ out)
{
    const int b = blockIdx.x, t = threadIdx.x;
    __shared__ float pxA[NN], pyA[NN], txA[MM], tyA[MM];   // 16 KB
    __shared__ __align__(16) unsigned sbuf[2][BAND_W];     // 96 KB
    __shared__ unsigned path[2048];                        // 8 KB
    __shared__ int sI, sJ, sN;
    __shared__ float wsum[4];

    for (int it = 0; it < 4; ++it) {
        const int idx = it * 256 + t;
        const float4 p4 = ((const float4*)preds)[(size_t)b * NN + idx];
        pxA[idx] = p4.x; pyA[idx] = p4.y;
        const float4 t4 = ((const float4*)targs)[(size_t)b * MM + idx];
        txA[idx] = t4.x; tyA[idx] = t4.y;
    }
    const unsigned* __restrict__ decB = wsu + (size_t)b * BAT_WORDS;

    // stage band 7 into sbuf[1]
    {
        uint4* d4 = (uint4*)sbuf[7 & 1];
        const uint4* s4 = (const uint4*)(decB + (size_t)7 * BAND_W);
        for (int k = t; k < BAND_W / 4; k += 256) d4[k] = s4[k];
    }
    if (t == 0) { sI = NN - 1; sJ = MM - 1; sN = 0; }
    __syncthreads();

    for (int r = 7; r >= 0; --r) {
        if (t == 0) {
            int i = sI, j = sJ, n = sN;
            if (i >= 0) {
                const unsigned* __restrict__ sd = sbuf[r & 1];
                const int iLow = r << 7;
                int cwidx = -1; unsigned cw = 0;
                while (true) {
                    path[n++] = ((unsigned)i << 16) | (unsigned)j;
                    if ((i | j) == 0) { i = -1; break; }
                    const int ll = (i & 127) >> 1;
                    const int ss = ll + (j & 127);
                    const int widx = (j >> 7) * PAN_WORDS + (ss >> 3) * 64 + ll;
                    if (widx != cwidx) { cw = sd[widx]; cwidx = widx; }
                    const unsigned m = (cw >> ((ss & 7) * 4 + (i & 1) * 2)) & 3u;
                    i -= (m != 2u); j -= (m != 1u);
                    if (i < iLow) break;
                }
            }
            sI = i; sJ = j; sN = n;
        } else if (r > 0) {
            // copy band r-1 into the other buffer while t0 walks band r
            uint4* d4 = (uint4*)sbuf[(r - 1) & 1];
            const uint4* s4 = (const uint4*)(decB + (size_t)(r - 1) * BAND_W);
            for (int k = t - 1; k < BAND_W / 4; k += 255) d4[k] = s4[k];
        }
        __syncthreads();
    }

    // parallel loss over the path (verbatim from proven kernel)
    const float sc0 = subcoef[0], sc1 = subcoef[1];
    const int n = sN;
    float acc = 0.0f;
    for (int p = t; p < n; p += 256) {
        const unsigned e = path[p];
        const int i = (int)(e >> 16), j = (int)(e & 0xffffu);
        acc += fabsf(pxA[i] - txA[j]) * sc0 + fabsf(pyA[i] - tyA[j]) * sc1;
    }
    #pragma unroll
    for (int o = 32; o > 0; o >>= 1) acc += __shfl_down(acc, o);
    if ((t & 63) == 0) wsum[t >> 6] = acc;
    __syncthreads();
    if (t == 0) atomicAdd(out, (wsum[0] + wsum[1]) + (wsum[2] + wsum[3]));
}

// =================== Legacy proven path (557us, needs 8MB) ===================
__device__ inline void bt_walk4(const unsigned* __restrict__ sdec, int roff,
                                int iLow, int& i, int& j, int& n,
                                unsigned* __restrict__ path)
{
    int ri = i >> 2, jc = j >> 2;
    unsigned w = sdec[(ri - roff) * 256 + jc];
    while (true) {
        const int base = (ri - roff) * 256 + jc;
        const unsigned wl = sdec[(jc > 0)    ? base - 1   : base];
        const unsigned wu = sdec[(ri > roff) ? base - 256 : base];
        const unsigned wd = sdec[(ri > roff && jc > 0) ? base - 257 : base];
        bool done = false, susp = false;
        while (true) {
            path[n++] = ((unsigned)i << 16) | (unsigned)j;
            if ((i | j) == 0) { done = true; break; }
            const unsigned m = (w >> (((i & 3) * 4 + (j & 3)) * 2)) & 3u;
            i -= (m != 2u); j -= (m != 1u);
            if (i < iLow) { susp = true; break; }
            if ((i >> 2) != ri || (j >> 2) != jc) break;
        }
        if (done || susp) break;
        const int nri = i >> 2, njc = j >> 2;
        w = (nri == ri) ? wl : ((njc == jc) ? wu : wd);
        ri = nri; jc = njc;
    }
}

#define RRL 4
#define CCL 4
#define LANES 64
#define NWAVE 4
#define TPBL (MM / 4)
#define NSUP (TPBL + LANES - 1)
#define LAG 72
#define TOTL (NSUP + (NWAVE - 1) * LAG)
#define DEPTH 32

__global__ __launch_bounds__(256, 1) void dtw_fused_legacy(
    const float* __restrict__ preds, const float* __restrict__ targs,
    const float* __restrict__ subcoef, unsigned* __restrict__ dec,
    float* __restrict__ out)
{
    const int b = blockIdx.x, t = threadIdx.x;
    const int l = t & 63, w = t >> 6;
    const float INF = __builtin_inff();

    __shared__ float pxA[NN], pyA[NN], txA[MM], tyA[MM];
    __shared__ float4 ring[NWAVE - 1][DEPTH];
    __shared__ unsigned sdec[128 * 256];
    __shared__ unsigned path[LPATH + 1];
    __shared__ int sI, sJ, sN;
    __shared__ float wsum[NWAVE];

    for (int it = 0; it < NN / 256; ++it) {
        const int idx = it * 256 + t;
        const float4 p4 = ((const float4*)preds)[(size_t)b * NN + idx];
        pxA[idx] = p4.x; pyA[idx] = p4.y;
        const float4 t4 = ((const float4*)targs)[(size_t)b * MM + idx];
        txA[idx] = t4.x; tyA[idx] = t4.y;
    }
    __syncthreads();

    const int i0 = (w << 8) + (l << 2);
    const float4 px4 = ((const float4*)pxA)[i0 >> 2];
    const float4 py4 = ((const float4*)pyA)[i0 >> 2];
    const float px[RRL] = {px4.x, px4.y, px4.z, px4.w};
    const float py[RRL] = {py4.x, py4.y, py4.z, py4.w};
    unsigned* __restrict__ decW =
        dec + (size_t)b * DEC_WORDS_PER_BATCH + ((size_t)w << 14) + (size_t)l;

    float Dp[RRL], Dbot[CCL], bv[CCL];
    #pragma unroll
    for (int r = 0; r < RRL; ++r) Dp[r] = INF;
    #pragma unroll
    for (int c = 0; c < CCL; ++c) { Dbot[c] = INF; bv[c] = INF; }
    float bndRet = (w == 0 && l == 0) ? 0.0f : INF;
    float4 gcur = make_float4(INF, INF, INF, INF);
    float4 tx4 = ((const float4*)txA)[0], ty4 = ((const float4*)tyA)[0];
    const float4* __restrict__ ringR = ring[(w > 0) ? (w - 1) : 0];

    for (int u = 0; u < TOTL; ++u) {
        const int ul = u - LAG * w;
        if (l == 0) {
            const bool gb = (w > 0) && (ul >= 0) && (ul < TPBL);
            bv[0] = gb ? gcur.x : INF; bv[1] = gb ? gcur.y : INF;
            bv[2] = gb ? gcur.z : INF; bv[3] = gb ? gcur.w : INF;
        }
        const bool act = (ul >= l) && (ul < l + TPBL);
        if (act) {
            const float cx[CCL] = {tx4.x, tx4.y, tx4.z, tx4.w};
            const float cy[CCL] = {ty4.x, ty4.y, ty4.z, ty4.w};
            float cost[RRL][CCL];
            #pragma unroll
            for (int c = 0; c < CCL; ++c)
                #pragma unroll
                for (int r = 0; r < RRL; ++r) {
                    const float dx = px[r] - cx[c], dy = py[r] - cy[c];
                    cost[r][c] = __builtin_amdgcn_sqrtf(dx * dx + dy * dy);
                }
            unsigned word = 0;
            #pragma unroll
            for (int c = 0; c < CCL; ++c) {
                float up = bv[c];
                float dg = (c == 0) ? bndRet : bv[c - 1];
                #pragma unroll
                for (int r = 0; r < RRL; ++r) {
                    const float lf = Dp[r];
                    const unsigned m = (dg <= up && dg <= lf) ? 0u
                                     : ((up <= lf) ? 1u : 2u);
                    const float D = cost[r][c] + fminf(dg, fminf(up, lf));
                    word |= m << ((r * 4 + c) * 2);
                    dg = lf; up = D; Dp[r] = D;
                }
                Dbot[c] = up;
            }
            decW[(ul & 255) << 6] = word;
            if (l == LANES - 1 && w < NWAVE - 1)
                ring[w][ul & (DEPTH - 1)] =
                    make_float4(Dbot[0], Dbot[1], Dbot[2], Dbot[3]);
        }
        bndRet = bv[CCL - 1];
        #pragma unroll
        for (int c = 0; c < CCL; ++c) bv[c] = __shfl_up(Dbot[c], 1);
        const int un = ul + 1;
        if (un >= l && un < l + TPBL) {
            const int jn = CCL * (un - l);
            tx4 = ((const float4*)txA)[jn >> 2];
            ty4 = ((const float4*)tyA)[jn >> 2];
        }
        if (w > 0 && un >= 0 && un < TPBL)
            gcur = ringR[(un + 63) & (DEPTH - 1)];
        if ((u & 7) == 7) __syncthreads();
    }

    __threadfence_block();
    __syncthreads();

    const unsigned* __restrict__ decB = dec + (size_t)b * DEC_WORDS_PER_BATCH;
    {
        const uint4* g4 = (const uint4*)(decB + 32768);
        for (int k = t; k < 8192; k += 256) {
            const uint4 v = g4[k];
            const int kb = k << 2;
            const int wv = kb >> 14;
            const int rem = kb & 16383;
            const int q = rem >> 6;
            const int lb = rem & 63;
            const unsigned wd[4] = {v.x, v.y, v.z, v.w};
            #pragma unroll
            for (int e = 0; e < 4; ++e) {
                const int ll = lb + e;
                const int row = (wv << 6) + ll;
                const int jc = (q - ll) & 255;
                sdec[(row << 8) + jc] = wd[e];
            }
        }
    }
    __syncthreads();
    if (t == 0) {
        int i = NN - 1, j = MM - 1, n = 0;
        bt_walk4(sdec, 128, 512, i, j, n, path);
        sI = i; sJ = j; sN = n;
    }
    __syncthreads();
    {
        const uint4* g4 = (const uint4*)decB;
        for (int k = t; k < 8192; k += 256) {
            const uint4 v = g4[k];
            const int kb = k << 2;
            const int wv = kb >> 14;
            const int rem = kb & 16383;
            const int q = rem >> 6;
            const int lb = rem & 63;
            const unsigned wd[4] = {v.x, v.y, v.z, v.w};
            #pragma unroll
            for (int e = 0; e < 4; ++e) {
                const int ll = lb + e;
                const int row = (wv << 6) + ll;
                const int jc = (q - ll) & 255;
                sdec[(row << 8) + jc] = wd[e];
            }
        }
    }
    __syncthreads();
    if (t == 0) {
        int i = sI, j = sJ, n = sN;
        bt_walk4(sdec, 0, 0, i, j, n, path);
        sN = n;
    }
    __syncthreads();

    const float sc0 = subcoef[0], sc1 = subcoef[1];
    const int n = sN;
    float acc = 0.0f;
    for (int p = t; p < n; p += 256) {
        const unsigned e = path[p];
        const int i = (int)(e >> 16), j = (int)(e & 0xffffu);
        acc += fabsf(pxA[i] - txA[j]) * sc0 + fabsf(pyA[i] - tyA[j]) * sc1;
    }
    #pragma unroll
    for (int o = 32; o > 0; o >>= 1) acc += __shfl_down(acc, o);
    if ((t & 63) == 0) wsum[t >> 6] = acc;
    __syncthreads();
    if (t == 0) atomicAdd(out, (wsum[0] + wsum[1]) + (wsum[2] + wsum[3]));
}

// ------------- Fallback (only if ws too small for everything) ----------------
__global__ __launch_bounds__(256) void dtw_fallback(
    const float* __restrict__ preds, const float* __restrict__ targs,
    const float* __restrict__ subcoef, unsigned* __restrict__ dec,
    float* __restrict__ out)
{
    const int b = blockIdx.x;
    const int t = threadIdx.x;
    const float INF = __builtin_inff();
    __shared__ float px[NN], py[NN];
    __shared__ float txy[2 * MM];
    __shared__ float bbuf[2][256];

    for (int it = 0; it < NN / 256; ++it) {
        const int idx = it * 256 + t;
        const float4 p4 = ((const float4*)preds)[(size_t)b * NN + idx];
        px[idx] = p4.x; py[idx] = p4.y;
        const float4 t4 = ((const float4*)targs)[(size_t)b * MM + idx];
        txy[2 * idx] = t4.x; txy[2 * idx + 1] = t4.y;
    }
    bbuf[0][t] = INF; bbuf[1][t] = INF;
    __syncthreads();

    float pxr[4], pyr[4], Dp[4];
    #pragma unroll
    for (int r = 0; r < 4; ++r) {
        pxr[r] = px[4 * t + r]; pyr[r] = py[4 * t + r]; Dp[r] = INF;
    }
    float dgB = (t == 0) ? 0.0f : INF;
    unsigned packed = 0;
    unsigned* decB = dec + (size_t)b * 65536;
    for (int s = 0; s < MM + 255; ++s) {
        const int j = s - t;
        const float upB = (t == 0) ? INF : bbuf[(s + 1) & 1][t - 1];
        if (j >= 0 && j < MM) {
            const float txj = txy[2 * j], tyj = txy[2 * j + 1];
            float up = upB, dg = dgB;
            unsigned mbits = 0;
            #pragma unroll
            for (int r = 0; r < 4; ++r) {
                const float dx = pxr[r] - txj, dy = pyr[r] - tyj;
                const float c = sqrtf(dx * dx + dy * dy);
                const float lf = Dp[r];
                const unsigned m = (dg <= up && dg <= lf) ? 0u
                                 : ((up <= lf) ? 1u : 2u);
                mbits |= m << (r * 8 + (j & 3) * 2);
                const float Dc = c + fminf(up, fminf(dg, lf));
                dg = lf; up = Dc; Dp[r] = Dc;
            }
            packed |= mbits;
            if ((j & 3) == 3) { decB[(unsigned)t * 256 + (j >> 2)] = packed; packed = 0; }
            bbuf[s & 1][t] = Dp[3];
        }
        dgB = upB;
        __syncthreads();
    }
    __threadfence_block();
    __syncthreads();
    if (t == 0) {
        const float sc0 = subcoef[0], sc1 = subcoef[1];
        int i = NN - 1, jj = MM - 1;
        float loss = 0.0f;
        int ti = i >> 2, tj = jj >> 2;
        unsigned wv = decB[ti * 256 + tj];
        while (true) {
            const int tjl = (tj > 0) ? tj - 1 : 0;
            const int til = (ti > 0) ? ti - 1 : 0;
            const unsigned wl = decB[ti * 256 + tjl];
            const unsigned wu = decB[til * 256 + tj];
            const unsigned wd = decB[til * 256 + tjl];
            bool done = false;
            while (true) {
                loss += fabsf(px[i] - txy[2 * jj]) * sc0
                      + fabsf(py[i] - txy[2 * jj + 1]) * sc1;
                if ((i | jj) == 0) { done = true; break; }
                const unsigned m = (wv >> (((i & 3) * 4 + (jj & 3)) * 2)) & 3u;
                i -= (m != 2u); jj -= (m != 1u);
                if ((i >> 2) != ti || (jj >> 2) != tj) break;
            }
            if (done) break;
            const int nti = i >> 2, ntj = jj >> 2;
            wv = (nti == ti) ? wl : ((ntj == tj) ? wu : wd);
            ti = nti; tj = ntj;
        }
        atomicAdd(out, loss);
    }
}

extern "C" void kernel_launch(void* const* d_in, const int* in_sizes, int n_in,
                              void* d_out, int out_size, void* d_ws, size_t ws_size,
                              hipStream_t stream) {
    const float* preds   = (const float*)d_in[0];
    const float* targs   = (const float*)d_in[1];
    const float* subcoef = (const float*)d_in[2];
    float* out = (float*)d_out;

    if (ws_size >= REQ_WS_NEW) {
        float* wsf = (float*)d_ws;
        init2<<<BATCH, 256, 0, stream>>>(wsf, out);
        for (int d = 0; d < GB + GH - 1; ++d) {
            const int r0 = (d > GH - 1) ? d - (GH - 1) : 0;
            const int r1 = (d < GB - 1) ? d : GB - 1;
            dim3 grid(r1 - r0 + 1, BATCH);
            dtw_panel<<<grid, 64, 0, stream>>>(preds, targs, wsf, d);
        }
        dtw_bt<<<BATCH, 256, 0, stream>>>(preds, targs, subcoef,
                                          (const unsigned*)d_ws, out);
    } else if (ws_size >= REQ_WS) {
        unsigned* dec = (unsigned*)d_ws;
        init_kernel<<<1, 1, 0, stream>>>(out);
        dtw_fused_legacy<<<BATCH, 256, 0, stream>>>(preds, targs, subcoef, dec, out);
    } else {
        unsigned* dec = (unsigned*)d_ws;
        init_kernel<<<1, 1, 0, stream>>>(out);
        dtw_fallback<<<BATCH, 256, 0, stream>>>(preds, targs, subcoef, dec, out);
    }
}